// Round 7
// baseline (960.904 us; speedup 1.0000x reference)
//
#include <hip/hip_runtime.h>

// 0.8*dice_loss(pred,target) + 0.2*soft_cldice_loss(pred,target)
// pred/target: (64,1,512,512) fp32 -> 1 fp32 scalar.
//
// soft_skeletonize = 10x: x = relu(x - relu(dil3(ero3(x)) - ero3(x)))
//   ero3 = 3x3 min-pool, x OOB -> +inf; dil3 = 3x3 max-pool, ero OOB -> -inf
//
// R7: both chains (128 images) per pass -> 5 stencil dispatches total,
// 1024 blocks (16 waves/CU). Dice sums fused into pass 1 via stage-1's own
// row loads. Atomic hotspot fix (R6's 131us outlier): block-level LDS
// pre-reduce + atomics spread over 64 cache-line-separated slots.
//
// Harness rules learned: d_ws too small -> state in __device__ BSS;
// never pass __device__ symbols as host-side kernel args (host shadow addr).

#define H 512
#define W 512
#define NIMG 64
#define TOT 128                      // both chains
#define IMG_ELEMS (H * W)
#define RSTRIPS 32
#define SROWS (H / RSTRIPS)          // 16 output rows per wave
#define NDICE_SLOTS 64

__device__ float g_A[(size_t)TOT * IMG_ELEMS];    // 128 MiB
__device__ float g_B[(size_t)TOT * IMG_ELEMS];    // 128 MiB
__device__ float g_acc[NIMG * 4];                 // per-image pairing sums
__device__ float g_dice[NDICE_SLOTS * 16];        // spread dice accumulators

#define SEL_A 2
#define SEL_B 3

struct F8 { float4 a, b; };          // 8 consecutive columns per lane

__device__ __forceinline__ F8 f8fill(float v) {
  F8 r; r.a = make_float4(v, v, v, v); r.b = r.a; return r;
}
__device__ __forceinline__ F8 f8min(const F8& x, const F8& y) {
  F8 r;
  r.a.x = fminf(x.a.x, y.a.x); r.a.y = fminf(x.a.y, y.a.y);
  r.a.z = fminf(x.a.z, y.a.z); r.a.w = fminf(x.a.w, y.a.w);
  r.b.x = fminf(x.b.x, y.b.x); r.b.y = fminf(x.b.y, y.b.y);
  r.b.z = fminf(x.b.z, y.b.z); r.b.w = fminf(x.b.w, y.b.w);
  return r;
}
__device__ __forceinline__ F8 f8max(const F8& x, const F8& y) {
  F8 r;
  r.a.x = fmaxf(x.a.x, y.a.x); r.a.y = fmaxf(x.a.y, y.a.y);
  r.a.z = fmaxf(x.a.z, y.a.z); r.a.w = fmaxf(x.a.w, y.a.w);
  r.b.x = fmaxf(x.b.x, y.b.x); r.b.y = fmaxf(x.b.y, y.b.y);
  r.b.z = fmaxf(x.b.z, y.b.z); r.b.w = fmaxf(x.b.w, y.b.w);
  return r;
}
// horizontal 3-tap min; L/R image edges see +inf
__device__ __forceinline__ F8 ero8(const F8& v, int lane) {
  float L = __shfl_up(v.b.w, 1, 64);
  if (lane == 0) L = __builtin_inff();
  float R = __shfl_down(v.a.x, 1, 64);
  if (lane == 63) R = __builtin_inff();
  F8 e;
  e.a.x = fminf(L,     fminf(v.a.x, v.a.y));
  e.a.y = fminf(v.a.x, fminf(v.a.y, v.a.z));
  e.a.z = fminf(v.a.y, fminf(v.a.z, v.a.w));
  e.a.w = fminf(v.a.z, fminf(v.a.w, v.b.x));
  e.b.x = fminf(v.a.w, fminf(v.b.x, v.b.y));
  e.b.y = fminf(v.b.x, fminf(v.b.y, v.b.z));
  e.b.z = fminf(v.b.y, fminf(v.b.z, v.b.w));
  e.b.w = fminf(v.b.z, fminf(v.b.w, R));
  return e;
}
// horizontal 3-tap max; edges see -inf
__device__ __forceinline__ F8 dil8(const F8& v, int lane) {
  float L = __shfl_up(v.b.w, 1, 64);
  if (lane == 0) L = -__builtin_inff();
  float R = __shfl_down(v.a.x, 1, 64);
  if (lane == 63) R = -__builtin_inff();
  F8 d;
  d.a.x = fmaxf(L,     fmaxf(v.a.x, v.a.y));
  d.a.y = fmaxf(v.a.x, fmaxf(v.a.y, v.a.z));
  d.a.z = fmaxf(v.a.y, fmaxf(v.a.z, v.a.w));
  d.a.w = fmaxf(v.a.z, fmaxf(v.a.w, v.b.x));
  d.b.x = fmaxf(v.a.w, fmaxf(v.b.x, v.b.y));
  d.b.y = fmaxf(v.b.x, fmaxf(v.b.y, v.b.z));
  d.b.z = fmaxf(v.b.y, fmaxf(v.b.z, v.b.w));
  d.b.w = fmaxf(v.b.z, fmaxf(v.b.w, R));
  return d;
}
__device__ __forceinline__ F8 f8relu_sub(const F8& x, const F8& y) {
  F8 r;
  r.a.x = fmaxf(x.a.x - y.a.x, 0.f); r.a.y = fmaxf(x.a.y - y.a.y, 0.f);
  r.a.z = fmaxf(x.a.z - y.a.z, 0.f); r.a.w = fmaxf(x.a.w - y.a.w, 0.f);
  r.b.x = fmaxf(x.b.x - y.b.x, 0.f); r.b.y = fmaxf(x.b.y - y.b.y, 0.f);
  r.b.z = fmaxf(x.b.z - y.b.z, 0.f); r.b.w = fmaxf(x.b.w - y.b.w, 0.f);
  return r;
}
__device__ __forceinline__ float f8dot(const F8& x, const float4& oa,
                                       const float4& ob) {
  return x.a.x * oa.x + x.a.y * oa.y + x.a.z * oa.z + x.a.w * oa.w
       + x.b.x * ob.x + x.b.y * ob.y + x.b.z * ob.z + x.b.w * ob.w;
}
__device__ __forceinline__ float f8sum(const F8& x) {
  return x.a.x + x.a.y + x.a.z + x.a.w + x.b.x + x.b.y + x.b.z + x.b.w;
}

// Two fused skeletonize iterations (register-pipelined, verified in R6).
// MODE 0: store z.
// MODE 1: store z; dice sums from stage-1's own row loads:
//   isPred: a0 += sum(x*t), a1 += sum(x)  (streams matching target row)
//   !isPred: a2 += sum(x)
// MODE 2: no store; a0 += sum(z*other), a1 += sum(z).
// Per-wave partials (wave-reduced) returned in out3.
template <int MODE>
__device__ __forceinline__ void skel2_core(
    const float* __restrict__ simg, float* __restrict__ dimg,
    const float* __restrict__ oimg, bool isPred, int r0, int lane,
    float out3[3]) {
  const float PINF = __builtin_inff();
  float a0 = 0.f, a1 = 0.f, a2 = 0.f;

  auto loadrow = [&](int r) -> F8 {
    F8 v;
    if (r >= 0 && r < H) {
      const float4* rp = (const float4*)(simg + (size_t)r * W);
      v.a = rp[lane * 2];
      v.b = rp[lane * 2 + 1];
      if (MODE == 1 && r >= r0 && r < r0 + SROWS) {  // each owned row once
        if (isPred) {
          const float4* tp = (const float4*)(oimg + (size_t)r * W);
          float4 ta = tp[lane * 2], tb = tp[lane * 2 + 1];
          a0 += f8dot(v, ta, tb);
          a1 += f8sum(v);
        } else {
          a2 += f8sum(v);
        }
      }
    } else {
      v = f8fill(PINF);
    }
    return v;
  };

  // ---- stage-1 rolling state, positioned to emit y[s] next; s = r0-2 ----
  int s = r0 - 2;
  F8 xa = loadrow(s - 2);
  F8 xb = loadrow(s - 1);
  F8 xc = loadrow(s);
  F8 xp = loadrow(s + 1);
  F8 xn = loadrow(s + 2);
  F8 em = ero8(f8min(xa, f8min(xb, xc)), lane);      // e[s-1]
  if (s - 1 < 0) em = f8fill(-PINF);
  F8 ec = ero8(f8min(xb, f8min(xc, xp)), lane);      // e[s]
  if (s < 0) ec = f8fill(-PINF);
  F8 pmaxA = f8max(em, ec);
  F8 pminA = f8min(xc, xp);

  auto step1 = [&]() -> F8 {                         // emits y[s], s++
    F8 ep = ero8(f8min(pminA, xn), lane);            // e[s+1]
    if (s + 1 < 0 || s + 1 >= H) ep = f8fill(-PINF);
    F8 dil = dil8(f8max(pmaxA, ep), lane);
    F8 y = f8relu_sub(xc, f8relu_sub(dil, ec));
    if (s < 0 || s >= H) y = f8fill(PINF);           // stage-2 sees +inf OOB
    pminA = f8min(xp, xn);
    pmaxA = f8max(ec, ep);
    xc = xp; xp = xn; xn = loadrow(s + 3);
    ec = ep;
    ++s;
    return y;
  };

  // ---- stage-2 warmup: y rows r0-2 .. r0+2 ----
  F8 ya = step1();
  F8 yb = step1();
  F8 yc = step1();
  F8 yp = step1();
  F8 yn = step1();
  F8 e2m = ero8(f8min(ya, f8min(yb, yc)), lane);     // e2[r0-1]
  if (r0 - 1 < 0) e2m = f8fill(-PINF);
  F8 e2c = ero8(f8min(yb, f8min(yc, yp)), lane);     // e2[r0]
  F8 pmax2 = f8max(e2m, e2c);
  F8 pmin2 = f8min(yc, yp);

  #pragma unroll 2
  for (int t = r0; t < r0 + SROWS; ++t) {
    F8 ynew = step1();                               // y[t+3]
    F8 e2p = ero8(f8min(pmin2, yn), lane);           // e2[t+1]
    if (t + 1 >= H) e2p = f8fill(-PINF);
    F8 d2 = dil8(f8max(pmax2, e2p), lane);
    F8 z = f8relu_sub(yc, f8relu_sub(d2, e2c));

    if (MODE == 2) {
      const float4* orp = (const float4*)(oimg + (size_t)t * W);
      float4 oa = orp[lane * 2];
      float4 ob = orp[lane * 2 + 1];
      a0 += f8dot(z, oa, ob);
      a1 += f8sum(z);
    } else {
      float4* op = (float4*)(dimg + (size_t)t * W);
      op[lane * 2]     = z.a;
      op[lane * 2 + 1] = z.b;
    }
    pmin2 = f8min(yp, yn);
    pmax2 = f8max(e2c, e2p);
    yc = yp; yp = yn; yn = ynew; e2c = e2p;
  }

  if (MODE != 0) {
    #pragma unroll
    for (int o = 32; o; o >>= 1) {
      a0 += __shfl_down(a0, o, 64);
      a1 += __shfl_down(a1, o, 64);
      if (MODE == 1) a2 += __shfl_down(a2, o, 64);
    }
    out3[0] = a0; out3[1] = a1; out3[2] = a2;
  }
}

// Pass 1: ext inputs -> g_A (iters 0,1 of both chains) + dice sums.
__global__ __launch_bounds__(256, 4) void pass_start(
    const float* __restrict__ pred, const float* __restrict__ target) {
  const int wid  = blockIdx.x * 4 + (threadIdx.x >> 6);
  const int lane = threadIdx.x & 63;
  const int u    = wid / RSTRIPS;          // 0..127: unit (chain element)
  const int r0   = (wid % RSTRIPS) * SROWS;
  const bool isPred = (u < NIMG);
  const float* src = isPred ? pred + (size_t)u * IMG_ELEMS
                            : target + (size_t)(u - NIMG) * IMG_ELEMS;
  const float* o = isPred ? target + (size_t)u * IMG_ELEMS : nullptr;
  float* dst = (float*)g_A + (size_t)u * IMG_ELEMS;

  float out3[3] = {0.f, 0.f, 0.f};
  skel2_core<1>(src, dst, o, isPred, r0, lane, out3);

  __shared__ float red[4][3];
  const int wave = threadIdx.x >> 6;
  if (lane == 0) {
    red[wave][0] = out3[0]; red[wave][1] = out3[1]; red[wave][2] = out3[2];
  }
  __syncthreads();
  if (threadIdx.x < 3) {
    float sv = red[0][threadIdx.x] + red[1][threadIdx.x] +
               red[2][threadIdx.x] + red[3][threadIdx.x];
    // spread over 64 cache-line-separated slots: 16 blocks/slot contention
    atomicAdd(&g_dice[(blockIdx.x & (NDICE_SLOTS - 1)) * 16 + threadIdx.x], sv);
  }
}

// Passes 2-4: plain fused double-iteration over all 128 units.
__global__ __launch_bounds__(256, 4) void pass_plain(int srcSel) {
  const float* src = (srcSel == SEL_A) ? (const float*)g_A : (const float*)g_B;
  float* dst = (srcSel == SEL_A) ? g_B : g_A;
  const int wid  = blockIdx.x * 4 + (threadIdx.x >> 6);
  const int lane = threadIdx.x & 63;
  const int u    = wid / RSTRIPS;
  const int r0   = (wid % RSTRIPS) * SROWS;
  skel2_core<0>(src + (size_t)u * IMG_ELEMS, dst + (size_t)u * IMG_ELEMS,
                nullptr, false, r0, lane, nullptr);
}

// Pass 5: g_B -> iters 8,9 fused with pairing reduction.
//   u<64  (cl = skel(pred)): sum(cl*target), sum(cl) -> g_acc[u*4+0,1]
//   u>=64 (st = skel(target)): sum(st*pred), sum(st) -> g_acc[(u-64)*4+2,3]
__global__ __launch_bounds__(256, 4) void pass_reduce(
    const float* __restrict__ pred, const float* __restrict__ target) {
  const int wid  = blockIdx.x * 4 + (threadIdx.x >> 6);
  const int lane = threadIdx.x & 63;
  const int u    = wid / RSTRIPS;
  const int r0   = (wid % RSTRIPS) * SROWS;
  const bool isPred = (u < NIMG);
  const int img = isPred ? u : u - NIMG;
  const int accBase = isPred ? 0 : 2;
  const float* src = (const float*)g_B + (size_t)u * IMG_ELEMS;
  const float* o = isPred ? target + (size_t)img * IMG_ELEMS
                          : pred + (size_t)img * IMG_ELEMS;

  float out3[3] = {0.f, 0.f, 0.f};
  skel2_core<2>(src, nullptr, o, isPred, r0, lane, out3);

  __shared__ float red[4][2];
  const int wave = threadIdx.x >> 6;
  if (lane == 0) { red[wave][0] = out3[0]; red[wave][1] = out3[1]; }
  __syncthreads();
  if (threadIdx.x < 2) {
    float sv = red[0][threadIdx.x] + red[1][threadIdx.x] +
               red[2][threadIdx.x] + red[3][threadIdx.x];
    atomicAdd(&g_acc[img * 4 + accBase + threadIdx.x], sv);  // 8 blocks/addr
  }
}

__global__ void zero_acc() {
  for (int i = threadIdx.x; i < NIMG * 4; i += 256) g_acc[i] = 0.0f;
  for (int i = threadIdx.x; i < NDICE_SLOTS * 16; i += 256) g_dice[i] = 0.0f;
}

__global__ void final_kernel(float* __restrict__ out) {
  const int lane = threadIdx.x;  // 64 threads = 64 images / 64 dice slots
  float s1 = g_acc[lane * 4 + 0], s2 = g_acc[lane * 4 + 1];
  float s3 = g_acc[lane * 4 + 2], s4 = g_acc[lane * 4 + 3];
  float iflat = (s1 + 1.0f) / (s2 + 1.0f);
  float tflat = (s3 + 1.0f) / (s4 + 1.0f);
  float prod = iflat * tflat;
  float ssum = iflat + tflat;
  float d0 = g_dice[lane * 16 + 0];
  float d1 = g_dice[lane * 16 + 1];
  float d2 = g_dice[lane * 16 + 2];
  #pragma unroll
  for (int o = 32; o; o >>= 1) {
    prod += __shfl_down(prod, o, 64);
    ssum += __shfl_down(ssum, o, 64);
    d0   += __shfl_down(d0, o, 64);
    d1   += __shfl_down(d1, o, 64);
    d2   += __shfl_down(d2, o, 64);
  }
  if (lane == 0) {
    float cldice = 1.0f - 2.0f * prod / ssum;
    float dice = 1.0f - (2.0f * d0 + 1e-6f) / (d1 + d2 + 1e-6f);
    out[0] = 0.8f * dice + 0.2f * cldice;
  }
}

extern "C" void kernel_launch(void* const* d_in, const int* in_sizes, int n_in,
                              void* d_out, int out_size, void* d_ws, size_t ws_size,
                              hipStream_t stream) {
  const float* pred   = (const float*)d_in[0];
  const float* target = (const float*)d_in[1];
  float* out = (float*)d_out;
  (void)d_ws; (void)ws_size;

  const int nblocks = TOT * RSTRIPS / 4;   // 1024 blocks of 4 waves

  zero_acc<<<1, 256, 0, stream>>>();
  // iters (0,1): ext -> A (+dice); (2,3): A->B; (4,5): B->A; (6,7): A->B;
  // (8,9): B -> fused pairing reduction
  pass_start<<<nblocks, 256, 0, stream>>>(pred, target);
  pass_plain<<<nblocks, 256, 0, stream>>>(SEL_A);
  pass_plain<<<nblocks, 256, 0, stream>>>(SEL_B);
  pass_plain<<<nblocks, 256, 0, stream>>>(SEL_A);
  pass_reduce<<<nblocks, 256, 0, stream>>>(pred, target);
  final_kernel<<<1, 64, 0, stream>>>(out);
}

// Round 8
// 439.095 us; speedup vs baseline: 2.1884x; 2.1884x over previous
//
#include <hip/hip_runtime.h>

// 0.8*dice_loss(pred,target) + 0.2*soft_cldice_loss(pred,target)
// pred/target: (64,1,512,512) fp32 -> 1 fp32 scalar.
//
// soft_skeletonize = 10x: x = relu(x - relu(dil3(ero3(x)) - ero3(x)))
//   ero3 = 3x3 min-pool, x OOB -> +inf; dil3 = 3x3 max-pool, ero OOB -> -inf
//
// R8 = R7 minus the self-inflicted wound: __launch_bounds__(256,4) capped
// VGPRs at 64 and spilled the ~100-float register pipeline to scratch
// (416 MB phantom WRITE_SIZE on a store-free kernel). Plain
// __launch_bounds__(256) restores ~130 VGPRs, no spill.
//
// Harness rules learned: d_ws too small -> state in __device__ BSS;
// never pass __device__ symbols as host-side kernel args (host shadow addr).

#define H 512
#define W 512
#define NIMG 64
#define TOT 128                      // both chains
#define IMG_ELEMS (H * W)
#define RSTRIPS 32
#define SROWS (H / RSTRIPS)          // 16 output rows per wave
#define NDICE_SLOTS 64

__device__ float g_A[(size_t)TOT * IMG_ELEMS];    // 128 MiB
__device__ float g_B[(size_t)TOT * IMG_ELEMS];    // 128 MiB
__device__ float g_acc[NIMG * 4];                 // per-image pairing sums
__device__ float g_dice[NDICE_SLOTS * 16];        // spread dice accumulators

#define SEL_A 2
#define SEL_B 3

struct F8 { float4 a, b; };          // 8 consecutive columns per lane

__device__ __forceinline__ F8 f8fill(float v) {
  F8 r; r.a = make_float4(v, v, v, v); r.b = r.a; return r;
}
__device__ __forceinline__ F8 f8min(const F8& x, const F8& y) {
  F8 r;
  r.a.x = fminf(x.a.x, y.a.x); r.a.y = fminf(x.a.y, y.a.y);
  r.a.z = fminf(x.a.z, y.a.z); r.a.w = fminf(x.a.w, y.a.w);
  r.b.x = fminf(x.b.x, y.b.x); r.b.y = fminf(x.b.y, y.b.y);
  r.b.z = fminf(x.b.z, y.b.z); r.b.w = fminf(x.b.w, y.b.w);
  return r;
}
__device__ __forceinline__ F8 f8max(const F8& x, const F8& y) {
  F8 r;
  r.a.x = fmaxf(x.a.x, y.a.x); r.a.y = fmaxf(x.a.y, y.a.y);
  r.a.z = fmaxf(x.a.z, y.a.z); r.a.w = fmaxf(x.a.w, y.a.w);
  r.b.x = fmaxf(x.b.x, y.b.x); r.b.y = fmaxf(x.b.y, y.b.y);
  r.b.z = fmaxf(x.b.z, y.b.z); r.b.w = fmaxf(x.b.w, y.b.w);
  return r;
}
// horizontal 3-tap min; L/R image edges see +inf
__device__ __forceinline__ F8 ero8(const F8& v, int lane) {
  float L = __shfl_up(v.b.w, 1, 64);
  if (lane == 0) L = __builtin_inff();
  float R = __shfl_down(v.a.x, 1, 64);
  if (lane == 63) R = __builtin_inff();
  F8 e;
  e.a.x = fminf(L,     fminf(v.a.x, v.a.y));
  e.a.y = fminf(v.a.x, fminf(v.a.y, v.a.z));
  e.a.z = fminf(v.a.y, fminf(v.a.z, v.a.w));
  e.a.w = fminf(v.a.z, fminf(v.a.w, v.b.x));
  e.b.x = fminf(v.a.w, fminf(v.b.x, v.b.y));
  e.b.y = fminf(v.b.x, fminf(v.b.y, v.b.z));
  e.b.z = fminf(v.b.y, fminf(v.b.z, v.b.w));
  e.b.w = fminf(v.b.z, fminf(v.b.w, R));
  return e;
}
// horizontal 3-tap max; edges see -inf
__device__ __forceinline__ F8 dil8(const F8& v, int lane) {
  float L = __shfl_up(v.b.w, 1, 64);
  if (lane == 0) L = -__builtin_inff();
  float R = __shfl_down(v.a.x, 1, 64);
  if (lane == 63) R = -__builtin_inff();
  F8 d;
  d.a.x = fmaxf(L,     fmaxf(v.a.x, v.a.y));
  d.a.y = fmaxf(v.a.x, fmaxf(v.a.y, v.a.z));
  d.a.z = fmaxf(v.a.y, fmaxf(v.a.z, v.a.w));
  d.a.w = fmaxf(v.a.z, fmaxf(v.a.w, v.b.x));
  d.b.x = fmaxf(v.a.w, fmaxf(v.b.x, v.b.y));
  d.b.y = fmaxf(v.b.x, fmaxf(v.b.y, v.b.z));
  d.b.z = fmaxf(v.b.y, fmaxf(v.b.z, v.b.w));
  d.b.w = fmaxf(v.b.z, fmaxf(v.b.w, R));
  return d;
}
__device__ __forceinline__ F8 f8relu_sub(const F8& x, const F8& y) {
  F8 r;
  r.a.x = fmaxf(x.a.x - y.a.x, 0.f); r.a.y = fmaxf(x.a.y - y.a.y, 0.f);
  r.a.z = fmaxf(x.a.z - y.a.z, 0.f); r.a.w = fmaxf(x.a.w - y.a.w, 0.f);
  r.b.x = fmaxf(x.b.x - y.b.x, 0.f); r.b.y = fmaxf(x.b.y - y.b.y, 0.f);
  r.b.z = fmaxf(x.b.z - y.b.z, 0.f); r.b.w = fmaxf(x.b.w - y.b.w, 0.f);
  return r;
}
__device__ __forceinline__ float f8dot(const F8& x, const float4& oa,
                                       const float4& ob) {
  return x.a.x * oa.x + x.a.y * oa.y + x.a.z * oa.z + x.a.w * oa.w
       + x.b.x * ob.x + x.b.y * ob.y + x.b.z * ob.z + x.b.w * ob.w;
}
__device__ __forceinline__ float f8sum(const F8& x) {
  return x.a.x + x.a.y + x.a.z + x.a.w + x.b.x + x.b.y + x.b.z + x.b.w;
}

// Two fused skeletonize iterations (register-pipelined, verified in R6).
// MODE 0: store z.
// MODE 1: store z; dice sums from stage-1's own row loads:
//   isPred: a0 += sum(x*t), a1 += sum(x)  (streams matching target row)
//   !isPred: a2 += sum(x)
// MODE 2: no store; a0 += sum(z*other), a1 += sum(z).
// Per-wave partials (wave-reduced) returned in out3.
template <int MODE>
__device__ __forceinline__ void skel2_core(
    const float* __restrict__ simg, float* __restrict__ dimg,
    const float* __restrict__ oimg, bool isPred, int r0, int lane,
    float out3[3]) {
  const float PINF = __builtin_inff();
  float a0 = 0.f, a1 = 0.f, a2 = 0.f;

  auto loadrow = [&](int r) -> F8 {
    F8 v;
    if (r >= 0 && r < H) {
      const float4* rp = (const float4*)(simg + (size_t)r * W);
      v.a = rp[lane * 2];
      v.b = rp[lane * 2 + 1];
      if (MODE == 1 && r >= r0 && r < r0 + SROWS) {  // each owned row once
        if (isPred) {
          const float4* tp = (const float4*)(oimg + (size_t)r * W);
          float4 ta = tp[lane * 2], tb = tp[lane * 2 + 1];
          a0 += f8dot(v, ta, tb);
          a1 += f8sum(v);
        } else {
          a2 += f8sum(v);
        }
      }
    } else {
      v = f8fill(PINF);
    }
    return v;
  };

  // ---- stage-1 rolling state, positioned to emit y[s] next; s = r0-2 ----
  int s = r0 - 2;
  F8 xa = loadrow(s - 2);
  F8 xb = loadrow(s - 1);
  F8 xc = loadrow(s);
  F8 xp = loadrow(s + 1);
  F8 xn = loadrow(s + 2);
  F8 em = ero8(f8min(xa, f8min(xb, xc)), lane);      // e[s-1]
  if (s - 1 < 0) em = f8fill(-PINF);
  F8 ec = ero8(f8min(xb, f8min(xc, xp)), lane);      // e[s]
  if (s < 0) ec = f8fill(-PINF);
  F8 pmaxA = f8max(em, ec);
  F8 pminA = f8min(xc, xp);

  auto step1 = [&]() -> F8 {                         // emits y[s], s++
    F8 ep = ero8(f8min(pminA, xn), lane);            // e[s+1]
    if (s + 1 < 0 || s + 1 >= H) ep = f8fill(-PINF);
    F8 dil = dil8(f8max(pmaxA, ep), lane);
    F8 y = f8relu_sub(xc, f8relu_sub(dil, ec));
    if (s < 0 || s >= H) y = f8fill(PINF);           // stage-2 sees +inf OOB
    pminA = f8min(xp, xn);
    pmaxA = f8max(ec, ep);
    xc = xp; xp = xn; xn = loadrow(s + 3);
    ec = ep;
    ++s;
    return y;
  };

  // ---- stage-2 warmup: y rows r0-2 .. r0+2 ----
  F8 ya = step1();
  F8 yb = step1();
  F8 yc = step1();
  F8 yp = step1();
  F8 yn = step1();
  F8 e2m = ero8(f8min(ya, f8min(yb, yc)), lane);     // e2[r0-1]
  if (r0 - 1 < 0) e2m = f8fill(-PINF);
  F8 e2c = ero8(f8min(yb, f8min(yc, yp)), lane);     // e2[r0]
  F8 pmax2 = f8max(e2m, e2c);
  F8 pmin2 = f8min(yc, yp);

  #pragma unroll 2
  for (int t = r0; t < r0 + SROWS; ++t) {
    F8 ynew = step1();                               // y[t+3]
    F8 e2p = ero8(f8min(pmin2, yn), lane);           // e2[t+1]
    if (t + 1 >= H) e2p = f8fill(-PINF);
    F8 d2 = dil8(f8max(pmax2, e2p), lane);
    F8 z = f8relu_sub(yc, f8relu_sub(d2, e2c));

    if (MODE == 2) {
      const float4* orp = (const float4*)(oimg + (size_t)t * W);
      float4 oa = orp[lane * 2];
      float4 ob = orp[lane * 2 + 1];
      a0 += f8dot(z, oa, ob);
      a1 += f8sum(z);
    } else {
      float4* op = (float4*)(dimg + (size_t)t * W);
      op[lane * 2]     = z.a;
      op[lane * 2 + 1] = z.b;
    }
    pmin2 = f8min(yp, yn);
    pmax2 = f8max(e2c, e2p);
    yc = yp; yp = yn; yn = ynew; e2c = e2p;
  }

  if (MODE != 0) {
    #pragma unroll
    for (int o = 32; o; o >>= 1) {
      a0 += __shfl_down(a0, o, 64);
      a1 += __shfl_down(a1, o, 64);
      if (MODE == 1) a2 += __shfl_down(a2, o, 64);
    }
    out3[0] = a0; out3[1] = a1; out3[2] = a2;
  }
}

// Pass 1: ext inputs -> g_A (iters 0,1 of both chains) + dice sums.
__global__ __launch_bounds__(256) void pass_start(
    const float* __restrict__ pred, const float* __restrict__ target) {
  const int wid  = blockIdx.x * 4 + (threadIdx.x >> 6);
  const int lane = threadIdx.x & 63;
  const int u    = wid / RSTRIPS;          // 0..127: unit (chain element)
  const int r0   = (wid % RSTRIPS) * SROWS;
  const bool isPred = (u < NIMG);
  const float* src = isPred ? pred + (size_t)u * IMG_ELEMS
                            : target + (size_t)(u - NIMG) * IMG_ELEMS;
  const float* o = isPred ? target + (size_t)u * IMG_ELEMS : nullptr;
  float* dst = (float*)g_A + (size_t)u * IMG_ELEMS;

  float out3[3] = {0.f, 0.f, 0.f};
  skel2_core<1>(src, dst, o, isPred, r0, lane, out3);

  __shared__ float red[4][3];
  const int wave = threadIdx.x >> 6;
  if (lane == 0) {
    red[wave][0] = out3[0]; red[wave][1] = out3[1]; red[wave][2] = out3[2];
  }
  __syncthreads();
  if (threadIdx.x < 3) {
    float sv = red[0][threadIdx.x] + red[1][threadIdx.x] +
               red[2][threadIdx.x] + red[3][threadIdx.x];
    // spread over 64 cache-line-separated slots: 16 blocks/slot contention
    atomicAdd(&g_dice[(blockIdx.x & (NDICE_SLOTS - 1)) * 16 + threadIdx.x], sv);
  }
}

// Passes 2-4: plain fused double-iteration over all 128 units.
__global__ __launch_bounds__(256) void pass_plain(int srcSel) {
  const float* src = (srcSel == SEL_A) ? (const float*)g_A : (const float*)g_B;
  float* dst = (srcSel == SEL_A) ? g_B : g_A;
  const int wid  = blockIdx.x * 4 + (threadIdx.x >> 6);
  const int lane = threadIdx.x & 63;
  const int u    = wid / RSTRIPS;
  const int r0   = (wid % RSTRIPS) * SROWS;
  skel2_core<0>(src + (size_t)u * IMG_ELEMS, dst + (size_t)u * IMG_ELEMS,
                nullptr, false, r0, lane, nullptr);
}

// Pass 5: g_B -> iters 8,9 fused with pairing reduction.
//   u<64  (cl = skel(pred)): sum(cl*target), sum(cl) -> g_acc[u*4+0,1]
//   u>=64 (st = skel(target)): sum(st*pred), sum(st) -> g_acc[(u-64)*4+2,3]
__global__ __launch_bounds__(256) void pass_reduce(
    const float* __restrict__ pred, const float* __restrict__ target) {
  const int wid  = blockIdx.x * 4 + (threadIdx.x >> 6);
  const int lane = threadIdx.x & 63;
  const int u    = wid / RSTRIPS;
  const int r0   = (wid % RSTRIPS) * SROWS;
  const bool isPred = (u < NIMG);
  const int img = isPred ? u : u - NIMG;
  const int accBase = isPred ? 0 : 2;
  const float* src = (const float*)g_B + (size_t)u * IMG_ELEMS;
  const float* o = isPred ? target + (size_t)img * IMG_ELEMS
                          : pred + (size_t)img * IMG_ELEMS;

  float out3[3] = {0.f, 0.f, 0.f};
  skel2_core<2>(src, nullptr, o, isPred, r0, lane, out3);

  __shared__ float red[4][2];
  const int wave = threadIdx.x >> 6;
  if (lane == 0) { red[wave][0] = out3[0]; red[wave][1] = out3[1]; }
  __syncthreads();
  if (threadIdx.x < 2) {
    float sv = red[0][threadIdx.x] + red[1][threadIdx.x] +
               red[2][threadIdx.x] + red[3][threadIdx.x];
    atomicAdd(&g_acc[img * 4 + accBase + threadIdx.x], sv);  // 8 blocks/addr
  }
}

__global__ void zero_acc() {
  for (int i = threadIdx.x; i < NIMG * 4; i += 256) g_acc[i] = 0.0f;
  for (int i = threadIdx.x; i < NDICE_SLOTS * 16; i += 256) g_dice[i] = 0.0f;
}

__global__ void final_kernel(float* __restrict__ out) {
  const int lane = threadIdx.x;  // 64 threads = 64 images / 64 dice slots
  float s1 = g_acc[lane * 4 + 0], s2 = g_acc[lane * 4 + 1];
  float s3 = g_acc[lane * 4 + 2], s4 = g_acc[lane * 4 + 3];
  float iflat = (s1 + 1.0f) / (s2 + 1.0f);
  float tflat = (s3 + 1.0f) / (s4 + 1.0f);
  float prod = iflat * tflat;
  float ssum = iflat + tflat;
  float d0 = g_dice[lane * 16 + 0];
  float d1 = g_dice[lane * 16 + 1];
  float d2 = g_dice[lane * 16 + 2];
  #pragma unroll
  for (int o = 32; o; o >>= 1) {
    prod += __shfl_down(prod, o, 64);
    ssum += __shfl_down(ssum, o, 64);
    d0   += __shfl_down(d0, o, 64);
    d1   += __shfl_down(d1, o, 64);
    d2   += __shfl_down(d2, o, 64);
  }
  if (lane == 0) {
    float cldice = 1.0f - 2.0f * prod / ssum;
    float dice = 1.0f - (2.0f * d0 + 1e-6f) / (d1 + d2 + 1e-6f);
    out[0] = 0.8f * dice + 0.2f * cldice;
  }
}

extern "C" void kernel_launch(void* const* d_in, const int* in_sizes, int n_in,
                              void* d_out, int out_size, void* d_ws, size_t ws_size,
                              hipStream_t stream) {
  const float* pred   = (const float*)d_in[0];
  const float* target = (const float*)d_in[1];
  float* out = (float*)d_out;
  (void)d_ws; (void)ws_size;

  const int nblocks = TOT * RSTRIPS / 4;   // 1024 blocks of 4 waves

  zero_acc<<<1, 256, 0, stream>>>();
  // iters (0,1): ext -> A (+dice); (2,3): A->B; (4,5): B->A; (6,7): A->B;
  // (8,9): B -> fused pairing reduction
  pass_start<<<nblocks, 256, 0, stream>>>(pred, target);
  pass_plain<<<nblocks, 256, 0, stream>>>(SEL_A);
  pass_plain<<<nblocks, 256, 0, stream>>>(SEL_B);
  pass_plain<<<nblocks, 256, 0, stream>>>(SEL_A);
  pass_reduce<<<nblocks, 256, 0, stream>>>(pred, target);
  final_kernel<<<1, 64, 0, stream>>>(out);
}